// Round 6
// baseline (1078.100 us; speedup 1.0000x reference)
//
#include <hip/hip_runtime.h>

#define N_NODES_C 100000
#define N_EDGES_C 600000
#define HIDDEN_C 128
#define K_HOPS_C 10
#define SCAN_B 98  // ceil(100000/1024)

typedef short short8 __attribute__((ext_vector_type(8)));   // 8 bf16 (4 VGPRs)
typedef float f32x16 __attribute__((ext_vector_type(16)));  // 32x32 accumulator
typedef unsigned uint2v __attribute__((ext_vector_type(2)));  // native vec2 for nontemporal
typedef float float4v __attribute__((ext_vector_type(4)));    // native vec4 for nontemporal

// ---- bf16 helpers (round-to-nearest-even pack, exact unpack) ----
__device__ __forceinline__ unsigned short f2bf(float f) {
    unsigned u = __float_as_uint(f);
    return (unsigned short)((u + 0x7FFFu + ((u >> 16) & 1u)) >> 16);
}
__device__ __forceinline__ float bf_lo(unsigned p) { return __uint_as_float(p << 16); }
__device__ __forceinline__ float bf_hi(unsigned p) { return __uint_as_float(p & 0xFFFF0000u); }

__device__ __forceinline__ void acc8(float* a, uint4 p, float w) {
    a[0] += w * bf_lo(p.x); a[1] += w * bf_hi(p.x);
    a[2] += w * bf_lo(p.y); a[3] += w * bf_hi(p.y);
    a[4] += w * bf_lo(p.z); a[5] += w * bf_hi(p.z);
    a[6] += w * bf_lo(p.w); a[7] += w * bf_hi(p.w);
}

// ---------------- degree count (in-degree over real edges) ----------------
__global__ void k_deg(const int* __restrict__ dst, int* __restrict__ deg, int E) {
    int e = blockIdx.x * blockDim.x + threadIdx.x;
    if (e < E) atomicAdd(&deg[dst[e]], 1);
}

// ---------------- multi-block exclusive scan, phase A ----------------------
__global__ __launch_bounds__(1024) void k_scan_a(const int* __restrict__ deg,
                                                 int* __restrict__ offs,
                                                 int* __restrict__ blksum,
                                                 float* __restrict__ dinv, int N) {
    __shared__ int wtot[16];
    int tid = threadIdx.x;
    int i = blockIdx.x * 1024 + tid;
    int lane = tid & 63;
    int wid = tid >> 6;
    int v = (i < N) ? deg[i] : 0;
    if (i < N) dinv[i] = rsqrtf((float)(v + 1));
    int incl = v;
#pragma unroll
    for (int d = 1; d < 64; d <<= 1) {
        int t = __shfl_up(incl, (unsigned)d, 64);
        if (lane >= d) incl += t;
    }
    if (lane == 63) wtot[wid] = incl;
    __syncthreads();
    int woff = 0, btot = 0;
#pragma unroll
    for (int w = 0; w < 16; ++w) {
        int t = wtot[w];
        if (w < wid) woff += t;
        btot += t;
    }
    if (i < N) offs[i] = woff + incl - v;
    if (tid == 0) blksum[blockIdx.x] = btot;
}

// ---------------- phase B: scan the 98 block sums (1 tiny block) -----------
__global__ __launch_bounds__(128) void k_scan_b(const int* __restrict__ blksum,
                                                int* __restrict__ blkoff,
                                                int* __restrict__ offs, int NB, int N) {
    __shared__ int wt[2];
    int t = threadIdx.x;
    int lane = t & 63;
    int w = t >> 6;
    int v = (t < NB) ? blksum[t] : 0;
    int incl = v;
#pragma unroll
    for (int d = 1; d < 64; d <<= 1) {
        int s = __shfl_up(incl, (unsigned)d, 64);
        if (lane >= d) incl += s;
    }
    if (lane == 63) wt[w] = incl;
    __syncthreads();
    int excl = incl - v + (w == 1 ? wt[0] : 0);
    if (t < NB) blkoff[t] = excl;
    if (t == 127) offs[N] = wt[0] + wt[1];
}

// ---------------- phase C: add block offsets, emit cursor ------------------
__global__ __launch_bounds__(1024) void k_scan_c(int* __restrict__ offs,
                                                 int* __restrict__ cursor,
                                                 const int* __restrict__ blkoff, int N) {
    int i = blockIdx.x * 1024 + threadIdx.x;
    if (i < N) {
        int v = offs[i] + blkoff[blockIdx.x];
        offs[i] = v;
        cursor[i] = v;
    }
}

// ---------------- CSR fill via atomic cursors (fused src+weight) ----------
__global__ void k_fill(const int* __restrict__ src, const int* __restrict__ dst,
                       const float* __restrict__ dinv, int* __restrict__ cursor,
                       uint2* __restrict__ csr, int E) {
    int e = blockIdx.x * blockDim.x + threadIdx.x;
    if (e < E) {
        int s = src[e], d = dst[e];
        int pos = atomicAdd(&cursor[d], 1);
        uint2 v;
        v.x = (unsigned)s;
        v.y = __float_as_uint(dinv[s] * dinv[d]);
        csr[pos] = v;
    }
}

// ---------------- h0 = bf16(x @ W^T + b), written CHUNK-SLICED -------------
// slab c holds nodes' features [16c,16c+16) : shorts [c*N*16 + node*16 + u]
__global__ __launch_bounds__(256) void k_gemm(const float* __restrict__ x,
                                              const float* __restrict__ W,
                                              const float* __restrict__ b,
                                              unsigned short* __restrict__ hsl, int N) {
    __shared__ unsigned short Wb[HIDDEN_C * HIDDEN_C];  // 32 KiB bf16
    int tid = threadIdx.x;
#pragma unroll
    for (int i = 0; i < 8; ++i) {
        int c = tid + 256 * i;
        int m = c >> 4;
        int g = c & 15;
        const float4* wsrc = (const float4*)W + m * 32 + g * 2;
        float4 wa = wsrc[0];
        float4 wb = wsrc[1];
        unsigned short t8[8];
        t8[0] = f2bf(wa.x); t8[1] = f2bf(wa.y); t8[2] = f2bf(wa.z); t8[3] = f2bf(wa.w);
        t8[4] = f2bf(wb.x); t8[5] = f2bf(wb.y); t8[6] = f2bf(wb.z); t8[7] = f2bf(wb.w);
        int gs = g ^ (m & 15);
        *(uint4*)&Wb[m * 128 + gs * 8] = *(const uint4*)t8;
    }
    __syncthreads();

    int lane = tid & 63;
    int wv = tid >> 6;
    int row0 = blockIdx.x * 128 + wv * 32;
    int m = lane & 31;
    int half = lane >> 5;

    int row = row0 + m;
    if (row >= N) row = N - 1;
    const float4* xrow = (const float4*)(x + (size_t)row * 128);

    f32x16 acc[4];
#pragma unroll
    for (int t = 0; t < 4; ++t)
#pragma unroll
        for (int r = 0; r < 16; ++r) acc[t][r] = 0.f;

    for (int s = 0; s < 8; ++s) {
        int kb = s * 16 + half * 8;
        float4 x0 = xrow[kb >> 2];
        float4 x1 = xrow[(kb >> 2) + 1];
        union { unsigned short u[8]; short8 v; } af;
        af.u[0] = f2bf(x0.x); af.u[1] = f2bf(x0.y); af.u[2] = f2bf(x0.z); af.u[3] = f2bf(x0.w);
        af.u[4] = f2bf(x1.x); af.u[5] = f2bf(x1.y); af.u[6] = f2bf(x1.z); af.u[7] = f2bf(x1.w);
        int g = kb >> 3;
#pragma unroll
        for (int t = 0; t < 4; ++t) {
            int r = t * 32 + m;
            short8 bfrag = *(const short8*)&Wb[r * 128 + ((g ^ (r & 15)) << 3)];
            acc[t] = __builtin_amdgcn_mfma_f32_32x32x16_bf16(af.v, bfrag, acc[t], 0, 0, 0);
        }
    }

    float bias[4];
#pragma unroll
    for (int t = 0; t < 4; ++t) bias[t] = b[t * 32 + m];
#pragma unroll
    for (int t = 0; t < 4; ++t) {
        int u = t * 32 + m;           // feature index
        int c = u >> 4;               // chunk
        int uu = u & 15;              // short within chunk
        size_t sbase = (size_t)c * N * 16;
#pragma unroll
        for (int r = 0; r < 16; ++r) {
            int rrow = (r & 3) + 8 * (r >> 2) + 4 * half;
            int node = row0 + rrow;
            if (node < N) {
                float v = acc[t][r] + bias[t];
                hsl[sbase + (size_t)node * 16 + uu] = f2bf(v);
            }
        }
    }
}

// ---- one APPNP hop over ONE feature chunk ---------------------------------
// chunk = blockIdx&7 -> lands on XCD (blockIdx&7) under round-robin dispatch:
// each XCD's gather working set = its 3.2MB slab (fits 4MiB L2, no cross-XCD).
// Wave = 4 nodes x 8 edge-slots x 2 lanes (16B each).
__global__ __launch_bounds__(256) void k_prop(const unsigned short* __restrict__ hin_sl,
                                              const unsigned short* __restrict__ h0_sl,
                                              unsigned short* __restrict__ hout_sl,
                                              float* __restrict__ hout_f,
                                              const int* __restrict__ offs,
                                              const uint2* __restrict__ csr,
                                              const float* __restrict__ dinv,
                                              int N, int final_hop) {
    int tid = threadIdx.x;
    int lane = tid & 63;
    int wv = tid >> 6;
    int chunk = blockIdx.x & 7;
    int nblk = blockIdx.x >> 3;
    int nsub = lane >> 4;        // node within wave (0..3)
    int q = (lane >> 1) & 7;     // edge slot (0..7)
    int f = lane & 1;            // 16B half of the 32B chunk row
    int node = nblk * 16 + wv * 4 + nsub;
    if (node >= N) return;

    const uint4* hin4 = (const uint4*)(hin_sl + (size_t)chunk * N * 16);
    const uint4* h04 = (const uint4*)(h0_sl + (size_t)chunk * N * 16);

    int beg = offs[node];
    int end = offs[node + 1];
    float dv = dinv[node];
    // hoisted streaming h0 read
    uint4 hq = h04[(size_t)node * 2 + f];

    float acc[8];
#pragma unroll
    for (int i = 0; i < 8; ++i) acc[i] = 0.f;

    // self-loop handled by slot 0
    if (q == 0) {
        uint4 p = hin4[(size_t)node * 2 + f];
        acc8(acc, p, dv * dv);
    }

    const uint2v* csrv = (const uint2v*)csr;
    for (int jb = beg; jb < end; jb += 8) {
        int j = jb + q;
        if (j < end) {
            uint2v e = __builtin_nontemporal_load(&csrv[j]);
            uint4 p = hin4[(size_t)e.x * 2 + f];
            acc8(acc, p, __uint_as_float(e.y));
        }
    }

    // reduce over the 8 edge slots (lane bits 1..3): xor 2, 4, 8
#pragma unroll
    for (int i = 0; i < 8; ++i) {
        acc[i] += __shfl_xor(acc[i], 2, 64);
        acc[i] += __shfl_xor(acc[i], 4, 64);
        acc[i] += __shfl_xor(acc[i], 8, 64);
    }

    if (q == 0) {
        float o[8];
        o[0] = 0.9f * acc[0] + 0.1f * bf_lo(hq.x);
        o[1] = 0.9f * acc[1] + 0.1f * bf_hi(hq.x);
        o[2] = 0.9f * acc[2] + 0.1f * bf_lo(hq.y);
        o[3] = 0.9f * acc[3] + 0.1f * bf_hi(hq.y);
        o[4] = 0.9f * acc[4] + 0.1f * bf_lo(hq.z);
        o[5] = 0.9f * acc[5] + 0.1f * bf_hi(hq.z);
        o[6] = 0.9f * acc[6] + 0.1f * bf_lo(hq.w);
        o[7] = 0.9f * acc[7] + 0.1f * bf_hi(hq.w);
        if (final_hop) {
            float* dst = hout_f + (size_t)node * 128 + chunk * 16 + f * 8;
            float4v v0; v0.x = o[0]; v0.y = o[1]; v0.z = o[2]; v0.w = o[3];
            float4v v1; v1.x = o[4]; v1.y = o[5]; v1.z = o[6]; v1.w = o[7];
            __builtin_nontemporal_store(v0, (float4v*)dst);
            __builtin_nontemporal_store(v1, (float4v*)(dst + 4));
        } else {
            uint4 p;
            p.x = (unsigned)f2bf(o[0]) | ((unsigned)f2bf(o[1]) << 16);
            p.y = (unsigned)f2bf(o[2]) | ((unsigned)f2bf(o[3]) << 16);
            p.z = (unsigned)f2bf(o[4]) | ((unsigned)f2bf(o[5]) << 16);
            p.w = (unsigned)f2bf(o[6]) | ((unsigned)f2bf(o[7]) << 16);
            ((uint4*)(hout_sl + (size_t)chunk * N * 16))[(size_t)node * 2 + f] = p;
        }
    }
}

extern "C" void kernel_launch(void* const* d_in, const int* in_sizes, int n_in,
                              void* d_out, int out_size, void* d_ws, size_t ws_size,
                              hipStream_t stream) {
    const float* x = (const float*)d_in[0];
    const int* edge = (const int*)d_in[1];  // [2, E]: [0]=src, [1]=dst
    const float* W = (const float*)d_in[2];
    const float* b = (const float*)d_in[3];
    float* out = (float*)d_out;

    const int N = N_NODES_C;
    const int E = N_EDGES_C;
    const int* src = edge;
    const int* dst = edge + E;

    char* ws = (char*)d_ws;
    size_t off = 0;
    auto carve = [&](size_t bytes) -> void* {
        void* p = ws + off;
        off = (off + bytes + 511) & ~(size_t)511;
        return p;
    };
    unsigned short* h0b = (unsigned short*)carve((size_t)N * HIDDEN_C * 2);  // sliced, 25.6 MB
    unsigned short* bA  = (unsigned short*)carve((size_t)N * HIDDEN_C * 2);
    unsigned short* bB  = (unsigned short*)carve((size_t)N * HIDDEN_C * 2);
    int*   deg     = (int*)  carve((size_t)N * sizeof(int));
    float* dinv    = (float*)carve((size_t)N * sizeof(float));
    int*   offs    = (int*)  carve((size_t)(N + 1) * sizeof(int));
    int*   cursor  = (int*)  carve((size_t)N * sizeof(int));
    uint2* csr     = (uint2*)carve((size_t)E * sizeof(uint2));
    int*   blksum  = (int*)  carve((size_t)SCAN_B * sizeof(int));
    int*   blkoff  = (int*)  carve((size_t)SCAN_B * sizeof(int));
    (void)ws_size;

    (void)hipMemsetAsync(deg, 0, (size_t)N * sizeof(int), stream);

    int eb = (E + 255) / 256;
    k_deg<<<eb, 256, 0, stream>>>(dst, deg, E);
    k_scan_a<<<SCAN_B, 1024, 0, stream>>>(deg, offs, blksum, dinv, N);
    k_scan_b<<<1, 128, 0, stream>>>(blksum, blkoff, offs, SCAN_B, N);
    k_scan_c<<<SCAN_B, 1024, 0, stream>>>(offs, cursor, blkoff, N);
    k_fill<<<eb, 256, 0, stream>>>(src, dst, dinv, cursor, csr, E);

    k_gemm<<<(N + 127) / 128, 256, 0, stream>>>(x, W, b, h0b, N);

    // 10 hops over 8 chunks each: grid = 8 * ceil(N/16)
    int nb = (N + 15) / 16;
    const unsigned short* hin = h0b;
    for (int k = 0; k < K_HOPS_C; ++k) {
        int fin = (k == K_HOPS_C - 1);
        unsigned short* houtb = ((k & 1) == 0) ? bA : bB;
        k_prop<<<nb * 8, 256, 0, stream>>>(hin, h0b, fin ? nullptr : houtb,
                                           fin ? out : nullptr,
                                           offs, csr, dinv, N, fin);
        hin = houtb;
    }
}

// Round 7
// 694.246 us; speedup vs baseline: 1.5529x; 1.5529x over previous
//
#include <hip/hip_runtime.h>

#define N_NODES_C 100000
#define N_EDGES_C 600000
#define HIDDEN_C 128
#define K_HOPS_C 10
#define SCAN_B 98  // ceil(100000/1024)

typedef short short8 __attribute__((ext_vector_type(8)));   // 8 bf16 (4 VGPRs)
typedef float f32x16 __attribute__((ext_vector_type(16)));  // 32x32 accumulator
typedef unsigned uint2v __attribute__((ext_vector_type(2)));
typedef unsigned uint4v __attribute__((ext_vector_type(4)));
typedef float float4v __attribute__((ext_vector_type(4)));

// ---- bf16 helpers (round-to-nearest-even pack, exact unpack) ----
__device__ __forceinline__ unsigned short f2bf(float f) {
    unsigned u = __float_as_uint(f);
    return (unsigned short)((u + 0x7FFFu + ((u >> 16) & 1u)) >> 16);
}
__device__ __forceinline__ float bf_lo(unsigned p) { return __uint_as_float(p << 16); }
__device__ __forceinline__ float bf_hi(unsigned p) { return __uint_as_float(p & 0xFFFF0000u); }

__device__ __forceinline__ void acc8(float* a, uint4 p, float w) {
    a[0] += w * bf_lo(p.x); a[1] += w * bf_hi(p.x);
    a[2] += w * bf_lo(p.y); a[3] += w * bf_hi(p.y);
    a[4] += w * bf_lo(p.z); a[5] += w * bf_hi(p.z);
    a[6] += w * bf_lo(p.w); a[7] += w * bf_hi(p.w);
}

// ---------------- degree count (in-degree over real edges) ----------------
__global__ void k_deg(const int* __restrict__ dst, int* __restrict__ deg, int E) {
    int e = blockIdx.x * blockDim.x + threadIdx.x;
    if (e < E) atomicAdd(&deg[dst[e]], 1);
}

// ---------------- multi-block exclusive scan, phase A ----------------------
__global__ __launch_bounds__(1024) void k_scan_a(const int* __restrict__ deg,
                                                 int* __restrict__ offs,
                                                 int* __restrict__ blksum,
                                                 float* __restrict__ dinv, int N) {
    __shared__ int wtot[16];
    int tid = threadIdx.x;
    int i = blockIdx.x * 1024 + tid;
    int lane = tid & 63;
    int wid = tid >> 6;
    int v = (i < N) ? deg[i] : 0;
    if (i < N) dinv[i] = rsqrtf((float)(v + 1));
    int incl = v;
#pragma unroll
    for (int d = 1; d < 64; d <<= 1) {
        int t = __shfl_up(incl, (unsigned)d, 64);
        if (lane >= d) incl += t;
    }
    if (lane == 63) wtot[wid] = incl;
    __syncthreads();
    int woff = 0, btot = 0;
#pragma unroll
    for (int w = 0; w < 16; ++w) {
        int t = wtot[w];
        if (w < wid) woff += t;
        btot += t;
    }
    if (i < N) offs[i] = woff + incl - v;
    if (tid == 0) blksum[blockIdx.x] = btot;
}

// ---------------- phase B: scan the 98 block sums (1 tiny block) -----------
__global__ __launch_bounds__(128) void k_scan_b(const int* __restrict__ blksum,
                                                int* __restrict__ blkoff,
                                                int* __restrict__ offs, int NB, int N) {
    __shared__ int wt[2];
    int t = threadIdx.x;
    int lane = t & 63;
    int w = t >> 6;
    int v = (t < NB) ? blksum[t] : 0;
    int incl = v;
#pragma unroll
    for (int d = 1; d < 64; d <<= 1) {
        int s = __shfl_up(incl, (unsigned)d, 64);
        if (lane >= d) incl += s;
    }
    if (lane == 63) wt[w] = incl;
    __syncthreads();
    int excl = incl - v + (w == 1 ? wt[0] : 0);
    if (t < NB) blkoff[t] = excl;
    if (t == 127) offs[N] = wt[0] + wt[1];
}

// ---------------- phase C: add block offsets, emit cursor ------------------
__global__ __launch_bounds__(1024) void k_scan_c(int* __restrict__ offs,
                                                 int* __restrict__ cursor,
                                                 const int* __restrict__ blkoff, int N) {
    int i = blockIdx.x * 1024 + threadIdx.x;
    if (i < N) {
        int v = offs[i] + blkoff[blockIdx.x];
        offs[i] = v;
        cursor[i] = v;
    }
}

// ---------------- CSR fill via atomic cursors (fused src+weight) ----------
__global__ void k_fill(const int* __restrict__ src, const int* __restrict__ dst,
                       const float* __restrict__ dinv, int* __restrict__ cursor,
                       uint2* __restrict__ csr, int E) {
    int e = blockIdx.x * blockDim.x + threadIdx.x;
    if (e < E) {
        int s = src[e], d = dst[e];
        int pos = atomicAdd(&cursor[d], 1);
        uint2 v;
        v.x = (unsigned)s;
        v.y = __float_as_uint(dinv[s] * dinv[d]);
        csr[pos] = v;
    }
}

// ---------------- h0b = bf16(x @ W^T + b) via 32x32x16 bf16 MFMA -----------
__global__ __launch_bounds__(256) void k_gemm(const float* __restrict__ x,
                                              const float* __restrict__ W,
                                              const float* __restrict__ b,
                                              unsigned short* __restrict__ hb, int N) {
    __shared__ unsigned short Wb[HIDDEN_C * HIDDEN_C];  // 32 KiB bf16
    int tid = threadIdx.x;
#pragma unroll
    for (int i = 0; i < 8; ++i) {
        int c = tid + 256 * i;
        int m = c >> 4;
        int g = c & 15;
        const float4* wsrc = (const float4*)W + m * 32 + g * 2;
        float4 wa = wsrc[0];
        float4 wb = wsrc[1];
        unsigned short t8[8];
        t8[0] = f2bf(wa.x); t8[1] = f2bf(wa.y); t8[2] = f2bf(wa.z); t8[3] = f2bf(wa.w);
        t8[4] = f2bf(wb.x); t8[5] = f2bf(wb.y); t8[6] = f2bf(wb.z); t8[7] = f2bf(wb.w);
        int gs = g ^ (m & 15);
        *(uint4*)&Wb[m * 128 + gs * 8] = *(const uint4*)t8;
    }
    __syncthreads();

    int lane = tid & 63;
    int wv = tid >> 6;
    int row0 = blockIdx.x * 128 + wv * 32;
    int m = lane & 31;
    int half = lane >> 5;

    int row = row0 + m;
    if (row >= N) row = N - 1;
    const float4* xrow = (const float4*)(x + (size_t)row * 128);

    f32x16 acc[4];
#pragma unroll
    for (int t = 0; t < 4; ++t)
#pragma unroll
        for (int r = 0; r < 16; ++r) acc[t][r] = 0.f;

    for (int s = 0; s < 8; ++s) {
        int kb = s * 16 + half * 8;
        float4 x0 = xrow[kb >> 2];
        float4 x1 = xrow[(kb >> 2) + 1];
        union { unsigned short u[8]; short8 v; } af;
        af.u[0] = f2bf(x0.x); af.u[1] = f2bf(x0.y); af.u[2] = f2bf(x0.z); af.u[3] = f2bf(x0.w);
        af.u[4] = f2bf(x1.x); af.u[5] = f2bf(x1.y); af.u[6] = f2bf(x1.z); af.u[7] = f2bf(x1.w);
        int g = kb >> 3;
#pragma unroll
        for (int t = 0; t < 4; ++t) {
            int r = t * 32 + m;
            short8 bfrag = *(const short8*)&Wb[r * 128 + ((g ^ (r & 15)) << 3)];
            acc[t] = __builtin_amdgcn_mfma_f32_32x32x16_bf16(af.v, bfrag, acc[t], 0, 0, 0);
        }
    }

    float bias[4];
#pragma unroll
    for (int t = 0; t < 4; ++t) bias[t] = b[t * 32 + m];
#pragma unroll
    for (int t = 0; t < 4; ++t) {
#pragma unroll
        for (int r = 0; r < 16; ++r) {
            int rrow = (r & 3) + 8 * (r >> 2) + 4 * half;
            int node = row0 + rrow;
            if (node < N) {
                float v = acc[t][r] + bias[t];
                hb[(size_t)node * 128 + t * 32 + m] = f2bf(v);
            }
        }
    }
}

// ---- one APPNP hop: hout = 0.9*(A_hat hin) + 0.1*h0  (all-bf16 state) -----
// Wave = 1 node. Lane L: edge-slot q=L>>4, row-chunk f=L&15.
// One dwordx4 gather fetches 4 edges' 256B rows; unroll x2 -> 8 in flight.
// Streaming operands (csr, h0b, mid-hop store) use nontemporal to keep L2
// for the gather lines.
__global__ __launch_bounds__(256) void k_prop(const uint4* __restrict__ hin4,
                                              const uint4* __restrict__ h04,
                                              uint4* __restrict__ hout_b,
                                              float* __restrict__ hout_f,
                                              const int* __restrict__ offs,
                                              const uint2* __restrict__ csr,
                                              const float* __restrict__ dinv,
                                              int N, int final_hop) {
    int tid = threadIdx.x;
    int lane = tid & 63;
    int wid = tid >> 6;
    int node = blockIdx.x * 4 + wid;
    if (node >= N) return;

    int q = lane >> 4;   // edge slot 0..3
    int f = lane & 15;   // 16B chunk within row

    int beg = offs[node];
    int end = offs[node + 1];

    // hoisted streaming h0 read (NT: no reuse)
    uint4v hqv = __builtin_nontemporal_load((const uint4v*)&h04[(size_t)node * 16 + f]);

    float acc[8];
#pragma unroll
    for (int i = 0; i < 8; ++i) acc[i] = 0.f;

    const uint2v* csrv = (const uint2v*)csr;

    int j = beg;
    for (; j + 8 <= end; j += 8) {
        int j0 = j + q;
        int j1 = j + 4 + q;
        uint2v e0 = __builtin_nontemporal_load(&csrv[j0]);
        uint2v e1 = __builtin_nontemporal_load(&csrv[j1]);
        uint4 p0 = hin4[(size_t)e0.x * 16 + f];
        uint4 p1 = hin4[(size_t)e1.x * 16 + f];
        acc8(acc, p0, __uint_as_float(e0.y));
        acc8(acc, p1, __uint_as_float(e1.y));
    }
    for (; j < end; j += 4) {
        int jj = j + q;
        if (jj < end) {
            uint2v e = __builtin_nontemporal_load(&csrv[jj]);
            uint4 p = hin4[(size_t)e.x * 16 + f];
            acc8(acc, p, __uint_as_float(e.y));
        }
    }
    // self-loop: only slot 0 contributes
    if (q == 0) {
        float dv = dinv[node];
        float ws = dv * dv;
        uint4 p = hin4[(size_t)node * 16 + f];
        acc8(acc, p, ws);
    }
    // reduce across the 4 edge slots (lanes ^16, ^32)
#pragma unroll
    for (int i = 0; i < 8; ++i) {
        acc[i] += __shfl_xor(acc[i], 16, 64);
        acc[i] += __shfl_xor(acc[i], 32, 64);
    }

    if (q == 0) {
        uint4 hq;
        hq.x = hqv.x; hq.y = hqv.y; hq.z = hqv.z; hq.w = hqv.w;
        float o[8];
        o[0] = 0.9f * acc[0] + 0.1f * bf_lo(hq.x);
        o[1] = 0.9f * acc[1] + 0.1f * bf_hi(hq.x);
        o[2] = 0.9f * acc[2] + 0.1f * bf_lo(hq.y);
        o[3] = 0.9f * acc[3] + 0.1f * bf_hi(hq.y);
        o[4] = 0.9f * acc[4] + 0.1f * bf_lo(hq.z);
        o[5] = 0.9f * acc[5] + 0.1f * bf_hi(hq.z);
        o[6] = 0.9f * acc[6] + 0.1f * bf_lo(hq.w);
        o[7] = 0.9f * acc[7] + 0.1f * bf_hi(hq.w);
        if (final_hop) {
            float* dst = hout_f + (size_t)node * 128 + f * 8;
            float4v v0; v0.x = o[0]; v0.y = o[1]; v0.z = o[2]; v0.w = o[3];
            float4v v1; v1.x = o[4]; v1.y = o[5]; v1.z = o[6]; v1.w = o[7];
            __builtin_nontemporal_store(v0, (float4v*)dst);
            __builtin_nontemporal_store(v1, (float4v*)(dst + 4));
        } else {
            uint4v p;
            p.x = (unsigned)f2bf(o[0]) | ((unsigned)f2bf(o[1]) << 16);
            p.y = (unsigned)f2bf(o[2]) | ((unsigned)f2bf(o[3]) << 16);
            p.z = (unsigned)f2bf(o[4]) | ((unsigned)f2bf(o[5]) << 16);
            p.w = (unsigned)f2bf(o[6]) | ((unsigned)f2bf(o[7]) << 16);
            __builtin_nontemporal_store(p, (uint4v*)&hout_b[(size_t)node * 16 + f]);
        }
    }
}

extern "C" void kernel_launch(void* const* d_in, const int* in_sizes, int n_in,
                              void* d_out, int out_size, void* d_ws, size_t ws_size,
                              hipStream_t stream) {
    const float* x = (const float*)d_in[0];
    const int* edge = (const int*)d_in[1];  // [2, E]: [0]=src, [1]=dst
    const float* W = (const float*)d_in[2];
    const float* b = (const float*)d_in[3];
    float* out = (float*)d_out;

    const int N = N_NODES_C;
    const int E = N_EDGES_C;
    const int* src = edge;
    const int* dst = edge + E;

    char* ws = (char*)d_ws;
    size_t off = 0;
    auto carve = [&](size_t bytes) -> void* {
        void* p = ws + off;
        off = (off + bytes + 511) & ~(size_t)511;
        return p;
    };
    unsigned short* h0b = (unsigned short*)carve((size_t)N * HIDDEN_C * 2);  // 25.6 MB
    unsigned short* bA  = (unsigned short*)carve((size_t)N * HIDDEN_C * 2);
    unsigned short* bB  = (unsigned short*)carve((size_t)N * HIDDEN_C * 2);
    int*   deg     = (int*)  carve((size_t)N * sizeof(int));
    float* dinv    = (float*)carve((size_t)N * sizeof(float));
    int*   offs    = (int*)  carve((size_t)(N + 1) * sizeof(int));
    int*   cursor  = (int*)  carve((size_t)N * sizeof(int));
    uint2* csr     = (uint2*)carve((size_t)E * sizeof(uint2));
    int*   blksum  = (int*)  carve((size_t)SCAN_B * sizeof(int));
    int*   blkoff  = (int*)  carve((size_t)SCAN_B * sizeof(int));
    (void)ws_size;

    (void)hipMemsetAsync(deg, 0, (size_t)N * sizeof(int), stream);

    int eb = (E + 255) / 256;
    k_deg<<<eb, 256, 0, stream>>>(dst, deg, E);
    k_scan_a<<<SCAN_B, 1024, 0, stream>>>(deg, offs, blksum, dinv, N);
    k_scan_b<<<1, 128, 0, stream>>>(blksum, blkoff, offs, SCAN_B, N);
    k_scan_c<<<SCAN_B, 1024, 0, stream>>>(offs, cursor, blkoff, N);
    k_fill<<<eb, 256, 0, stream>>>(src, dst, dinv, cursor, csr, E);

    k_gemm<<<(N + 127) / 128, 256, 0, stream>>>(x, W, b, h0b, N);

    // 10 hops: hops 1..9 write bf16 ping-pong, hop 10 writes fp32 d_out
    const uint4* hin = (const uint4*)h0b;
    for (int k = 0; k < K_HOPS_C; ++k) {
        int fin = (k == K_HOPS_C - 1);
        uint4* houtb = ((k & 1) == 0) ? (uint4*)bA : (uint4*)bB;
        k_prop<<<(N + 3) / 4, 256, 0, stream>>>(hin, (const uint4*)h0b,
                                                fin ? nullptr : houtb,
                                                fin ? out : nullptr,
                                                offs, csr, dinv, N, fin);
        hin = houtb;
    }
}